// Round 7
// baseline (197.184 us; speedup 1.0000x reference)
//
#include <hip/hip_runtime.h>
#include <stdint.h>

#define DF 32
#define BN 256               // nodes per bucket (dst >> 8)
#define MAXB 512             // max buckets on fast path (nN <= 131072)
#define CHUNK 4096           // edges per partition WG
typedef unsigned long long u64;
typedef unsigned short u16;

static __device__ __forceinline__ u16 f2bf(float x) {     // RTN-even
    unsigned u = __float_as_uint(x);
    return (u16)((u + 0x7fff + ((u >> 16) & 1)) >> 16);
}
static __device__ __forceinline__ float bf2f(u16 b) {
    return __uint_as_float((unsigned)b << 16);
}

__global__ void k_zero(int* __restrict__ p, int n) {
    int i = blockIdx.x * blockDim.x + threadIdx.x;
    if (i < n) p[i] = 0;
}

// ======================= bucket partition prepass =======================

__global__ void k_bcount(const int* __restrict__ dst, int* __restrict__ bcnt,
                         int nE, int nbuck) {
    __shared__ int h[MAXB];
    for (int i = threadIdx.x; i < MAXB; i += blockDim.x) h[i] = 0;
    __syncthreads();
    for (int i = blockIdx.x * blockDim.x + threadIdx.x; i < nE;
         i += gridDim.x * blockDim.x)
        atomicAdd(&h[dst[i] >> 8], 1);
    __syncthreads();
    for (int i = threadIdx.x; i < nbuck; i += blockDim.x)
        if (h[i]) atomicAdd(&bcnt[i], h[i]);
}

__global__ void k_bscan(const int* __restrict__ bcnt, int* __restrict__ bptr,
                        int* __restrict__ bcur, int nbuck) {
    __shared__ int a[MAXB], b[MAXB];
    int t = threadIdx.x;
    int v = (t < nbuck) ? bcnt[t] : 0;
    a[t] = v;
    __syncthreads();
    int* pin = a; int* pout = b;
    for (int off = 1; off < MAXB; off <<= 1) {
        pout[t] = pin[t] + ((t >= off) ? pin[t - off] : 0);
        __syncthreads();
        int* tmp = pin; pin = pout; pout = tmp;
    }
    int inc = pin[t];
    if (t < nbuck) { bptr[t] = inc - v; bcur[t] = inc - v; }
    if (t == nbuck - 1) bptr[nbuck] = inc;
}

// record = w(f32)<<32 | src<<8 | localDst  (needs nN < 2^24)
__global__ __launch_bounds__(512)
void k_bpart(const int* __restrict__ src, const int* __restrict__ dst,
             const float* __restrict__ w, int* __restrict__ bcur,
             u64* __restrict__ rec_g, int nE, int nbuck) {
    __shared__ u64 rec[CHUNK];
    __shared__ unsigned short rb[CHUNK];
    __shared__ int hist[MAXB], sa[MAXB], sb[MAXB], goff[MAXB], cur[MAXB];
    int t = threadIdx.x;
    int base = blockIdx.x * CHUNK;
    int cnt = min(CHUNK, nE - base);

    hist[t] = 0;
    __syncthreads();

    int myb[8]; u64 myrec[8];
#pragma unroll
    for (int j = 0; j < 8; j++) {
        int i = t + j * 512;
        if (i < cnt) {
            int d = dst[base + i];
            myb[j] = d >> 8;
            myrec[j] = ((u64)__float_as_uint(w[base + i]) << 32)
                     | ((u64)(unsigned)src[base + i] << 8)
                     | (u64)(d & (BN - 1));
            atomicAdd(&hist[myb[j]], 1);
        } else myb[j] = -1;
    }
    __syncthreads();

    int v = hist[t];
    sa[t] = v;
    __syncthreads();
    int* pin = sa; int* pout = sb;
    for (int off = 1; off < MAXB; off <<= 1) {
        pout[t] = pin[t] + ((t >= off) ? pin[t - off] : 0);
        __syncthreads();
        int* tmp = pin; pin = pout; pout = tmp;
    }
    int excl = pin[t] - v;
    cur[t] = excl;
    int g = 0;
    if (t < nbuck && v > 0) g = atomicAdd(&bcur[t], v);
    goff[t] = g - excl;
    __syncthreads();

#pragma unroll
    for (int j = 0; j < 8; j++) {
        if (myb[j] >= 0) {
            int p = atomicAdd(&cur[myb[j]], 1);
            rec[p] = myrec[j];
            rb[p] = (unsigned short)myb[j];
        }
    }
    __syncthreads();

    for (int r = t; r < cnt; r += 512) {
        int bb = rb[r];
        rec_g[goff[bb] + r] = rec[r];
    }
}

// one WG per bucket: exact CSR from bucket-sorted rec_g.
// packed = w(f32)<<32 | (src * 64)   (byte offset into bf16 feature matrix)
__global__ __launch_bounds__(512)
void k_csr(const int* __restrict__ bptr, const u64* __restrict__ rec_g,
           int* __restrict__ rowptr, u64* __restrict__ packed, int nN, int nbuck) {
    __shared__ int cnt[BN], excl[BN];
    int b = blockIdx.x;
    int t = threadIdx.x;
    int s0 = bptr[b], s1 = bptr[b + 1];
    if (t < BN) cnt[t] = 0;
    __syncthreads();
    for (int i = s0 + t; i < s1; i += 512)
        atomicAdd(&cnt[(int)(rec_g[i] & (BN - 1))], 1);
    __syncthreads();
    if (t < BN) excl[t] = cnt[t];
    __syncthreads();
    for (int off = 1; off < BN; off <<= 1) {
        int u = 0;
        if (t < BN && t >= off) u = excl[t - off];
        __syncthreads();
        if (t < BN) excl[t] += u;
        __syncthreads();
    }
    int nodeBase = b * BN;
    if (t < BN) {
        int e = excl[t] - cnt[t];
        if (nodeBase + t < nN) rowptr[nodeBase + t] = s0 + e;
        cnt[t] = e;
    }
    if (b == nbuck - 1 && t == 0) rowptr[nN] = s1;
    __syncthreads();
    for (int i = s0 + t; i < s1; i += 512) {
        u64 r = rec_g[i];
        int ld = (int)(r & (BN - 1));
        int pos = s0 + atomicAdd(&cnt[ld], 1);
        packed[pos] = (r & 0xffffffff00000000ull) | (((r >> 8) & 0xffffffull) << 6);
    }
}

// f32 -> bf16 cast (4 elems/thread)
__global__ void k_cast(const float* __restrict__ x, u16* __restrict__ y, int n4) {
    int i = blockIdx.x * blockDim.x + threadIdx.x;
    if (i >= n4) return;
    float4 v = reinterpret_cast<const float4*>(x)[i];
    ushort4 o;
    o.x = f2bf(v.x); o.y = f2bf(v.y); o.z = f2bf(v.z); o.w = f2bf(v.w);
    reinterpret_cast<ushort4*>(y)[i] = o;
}

// ======================= pull SpMM (bf16 gathers, masked unroll-8) ===========
// half-wave per node: lane f owns feature f. All edge batches are uniform
// 8-wide with clamped indices + zeroed OOB weights -> no serial remainder;
// ceil(deg/8) latency round-trips per node, 8 gathers in flight.
// MODE: 0 first (out = emb+acc, hn=bf16(acc)), 1 mid (out+=acc, hn=bf16(acc)),
// 2 last (out = (out+acc)*0.25)
template <int MODE>
__global__ void k_pull(const int* __restrict__ rowptr, const u64* __restrict__ packed,
                       const u16* __restrict__ h16, u16* __restrict__ hn16,
                       const float* __restrict__ emb, float* __restrict__ out, int n) {
    int gid = blockIdx.x * blockDim.x + threadIdx.x;
    int node = gid >> 5;
    int f = gid & 31;
    if (node >= n) return;
    int s0 = rowptr[node], s1 = rowptr[node + 1];
    const char* hb = (const char*)h16;
    float a0 = 0.f, a1 = 0.f, a2 = 0.f, a3 = 0.f,
          a4 = 0.f, a5 = 0.f, a6 = 0.f, a7 = 0.f;
    for (int i = s0; i < s1; i += 8) {
        u64 p0, p1, p2, p3, p4, p5, p6, p7;
        int lim = s1 - 1;
        p0 = packed[i];
        p1 = packed[i + 1 < s1 ? i + 1 : lim];
        p2 = packed[i + 2 < s1 ? i + 2 : lim];
        p3 = packed[i + 3 < s1 ? i + 3 : lim];
        p4 = packed[i + 4 < s1 ? i + 4 : lim];
        p5 = packed[i + 5 < s1 ? i + 5 : lim];
        p6 = packed[i + 6 < s1 ? i + 6 : lim];
        p7 = packed[i + 7 < s1 ? i + 7 : lim];
        float v0 = bf2f(*(const u16*)(hb + (unsigned)(p0 & 0xffffffffu) + f * 2));
        float v1 = bf2f(*(const u16*)(hb + (unsigned)(p1 & 0xffffffffu) + f * 2));
        float v2 = bf2f(*(const u16*)(hb + (unsigned)(p2 & 0xffffffffu) + f * 2));
        float v3 = bf2f(*(const u16*)(hb + (unsigned)(p3 & 0xffffffffu) + f * 2));
        float v4 = bf2f(*(const u16*)(hb + (unsigned)(p4 & 0xffffffffu) + f * 2));
        float v5 = bf2f(*(const u16*)(hb + (unsigned)(p5 & 0xffffffffu) + f * 2));
        float v6 = bf2f(*(const u16*)(hb + (unsigned)(p6 & 0xffffffffu) + f * 2));
        float v7 = bf2f(*(const u16*)(hb + (unsigned)(p7 & 0xffffffffu) + f * 2));
        float w0 = __uint_as_float((unsigned)(p0 >> 32));
        float w1 = (i + 1 < s1) ? __uint_as_float((unsigned)(p1 >> 32)) : 0.f;
        float w2 = (i + 2 < s1) ? __uint_as_float((unsigned)(p2 >> 32)) : 0.f;
        float w3 = (i + 3 < s1) ? __uint_as_float((unsigned)(p3 >> 32)) : 0.f;
        float w4 = (i + 4 < s1) ? __uint_as_float((unsigned)(p4 >> 32)) : 0.f;
        float w5 = (i + 5 < s1) ? __uint_as_float((unsigned)(p5 >> 32)) : 0.f;
        float w6 = (i + 6 < s1) ? __uint_as_float((unsigned)(p6 >> 32)) : 0.f;
        float w7 = (i + 7 < s1) ? __uint_as_float((unsigned)(p7 >> 32)) : 0.f;
        a0 += w0 * v0; a1 += w1 * v1; a2 += w2 * v2; a3 += w3 * v3;
        a4 += w4 * v4; a5 += w5 * v5; a6 += w6 * v6; a7 += w7 * v7;
    }
    float acc = ((a0 + a1) + (a2 + a3)) + ((a4 + a5) + (a6 + a7));
    size_t o = (size_t)node * DF + f;
    if (MODE == 0)      { hn16[o] = f2bf(acc); out[o] = emb[o] + acc; }
    else if (MODE == 1) { hn16[o] = f2bf(acc); out[o] += acc; }
    else                { out[o] = (out[o] + acc) * 0.25f; }
}

// ======================= fallback (R1 atomic path, f32) =======================

__global__ void spmm_scatter(const int* __restrict__ src, const int* __restrict__ dst,
                             const float* __restrict__ w, const float* __restrict__ h,
                             float* __restrict__ hn, int nE) {
    int i = blockIdx.x * blockDim.x + threadIdx.x;
    int total = nE * 8;
    if (i >= total) return;
    int e = i >> 3, g = i & 7;
    int s = src[e], t = dst[e];
    float wt = w[e];
    float4 v = reinterpret_cast<const float4*>(h)[(size_t)s * 8 + g];
    float* p = hn + (size_t)t * DF + g * 4;
    atomicAdd(p + 0, v.x * wt); atomicAdd(p + 1, v.y * wt);
    atomicAdd(p + 2, v.z * wt); atomicAdd(p + 3, v.w * wt);
}
__global__ void accum_first(const float* __restrict__ emb, const float* __restrict__ hn,
                            float* __restrict__ out, int n4) {
    int i = blockIdx.x * blockDim.x + threadIdx.x;
    if (i >= n4) return;
    float4 a = reinterpret_cast<const float4*>(emb)[i];
    float4 b = reinterpret_cast<const float4*>(hn)[i];
    reinterpret_cast<float4*>(out)[i] = make_float4(a.x+b.x, a.y+b.y, a.z+b.z, a.w+b.w);
}
__global__ void accum_mid(const float* __restrict__ hn, float* __restrict__ out, int n4) {
    int i = blockIdx.x * blockDim.x + threadIdx.x;
    if (i >= n4) return;
    float4 a = reinterpret_cast<float4*>(out)[i];
    float4 b = reinterpret_cast<const float4*>(hn)[i];
    reinterpret_cast<float4*>(out)[i] = make_float4(a.x+b.x, a.y+b.y, a.z+b.z, a.w+b.w);
}
__global__ void accum_last(const float* __restrict__ hn, float* __restrict__ out, int n4) {
    int i = blockIdx.x * blockDim.x + threadIdx.x;
    if (i >= n4) return;
    float4 a = reinterpret_cast<float4*>(out)[i];
    float4 b = reinterpret_cast<const float4*>(hn)[i];
    reinterpret_cast<float4*>(out)[i] = make_float4((a.x+b.x)*0.25f, (a.y+b.y)*0.25f,
                                                    (a.z+b.z)*0.25f, (a.w+b.w)*0.25f);
}

// ======================= launch =======================

extern "C" void kernel_launch(void* const* d_in, const int* in_sizes, int n_in,
                              void* d_out, int out_size, void* d_ws, size_t ws_size,
                              hipStream_t stream) {
    const float* emb = (const float*)d_in[0];
    const int*   src = (const int*)d_in[1];
    const int*   dst = (const int*)d_in[2];
    const float* w   = (const float*)d_in[3];
    float* out = (float*)d_out;

    const int nN = in_sizes[0] / DF;
    const int nE = in_sizes[1];
    const int nbuck = (nN + BN - 1) / BN;
    const size_t hbytes  = (size_t)nN * DF * sizeof(float);   // f32 matrix
    const size_t h16b    = (size_t)nN * DF * 2;               // bf16 matrix

    char* ws = (char*)d_ws;
    u16* E16 = (u16*)ws;
    u16* B16 = (u16*)(ws + h16b);
    u16* A16 = (u16*)(ws + 2 * h16b);
    u64* rec_g = (u64*)(ws + h16b);          // overlaps B16/A16; dead before pulls
    size_t recb = (((size_t)nE * 8 + 63) / 64) * 64;
    size_t off_pk = h16b + (recb > 2 * h16b ? recb : 2 * h16b);
    u64* packed = (u64*)(ws + off_pk);
    size_t roff = off_pk + recb;
    int* rowptr = (int*)(ws + roff);
    size_t boff = roff + (((size_t)(nN + 1) * 4 + 63) / 64) * 64;
    int* bcnt = (int*)(ws + boff);
    int* bptr = bcnt + MAXB;
    int* bcur = bptr + MAXB + 1;
    const size_t need = boff + (size_t)(3 * MAXB + 1) * 4;

    const dim3 blk(256);

    if (nbuck <= MAXB && nN < (1 << 24) && ws_size >= need) {
        const int n4 = nN * DF / 4;
        k_zero<<<(MAXB + 255) / 256, blk, 0, stream>>>(bcnt, MAXB);
        k_cast<<<(n4 + 255) / 256, blk, 0, stream>>>(emb, E16, n4);
        k_bcount<<<512, blk, 0, stream>>>(dst, bcnt, nE, nbuck);
        k_bscan<<<1, MAXB, 0, stream>>>(bcnt, bptr, bcur, nbuck);
        k_bpart<<<(nE + CHUNK - 1) / CHUNK, 512, 0, stream>>>(src, dst, w, bcur,
                                                              rec_g, nE, nbuck);
        k_csr<<<nbuck, 512, 0, stream>>>(bptr, rec_g, rowptr, packed, nN, nbuck);

        const int pgrid = (nN * 32 + 255) / 256;
        k_pull<0><<<pgrid, blk, 0, stream>>>(rowptr, packed, E16, B16, emb, out, nN);
        k_pull<1><<<pgrid, blk, 0, stream>>>(rowptr, packed, B16, A16, emb, out, nN);
        k_pull<2><<<pgrid, blk, 0, stream>>>(rowptr, packed, A16, B16, emb, out, nN);
    } else {
        float* A = (float*)ws;
        float* B = (float*)(ws + hbytes);
        const int n4 = nN * DF / 4;
        const int sgrid = (nE * 8 + 255) / 256;
        const int agrid = (n4 + 255) / 256;
        hipMemsetAsync(B, 0, hbytes, stream);
        spmm_scatter<<<sgrid, blk, 0, stream>>>(src, dst, w, emb, B, nE);
        accum_first<<<agrid, blk, 0, stream>>>(emb, B, out, n4);
        hipMemsetAsync(A, 0, hbytes, stream);
        spmm_scatter<<<sgrid, blk, 0, stream>>>(src, dst, w, B, A, nE);
        accum_mid<<<agrid, blk, 0, stream>>>(A, out, n4);
        hipMemsetAsync(B, 0, hbytes, stream);
        spmm_scatter<<<sgrid, blk, 0, stream>>>(src, dst, w, A, B, nE);
        accum_last<<<agrid, blk, 0, stream>>>(B, out, n4);
    }
}